// Round 1
// baseline (2404.477 us; speedup 1.0000x reference)
//
#include <hip/hip_runtime.h>

#define S 2048
#define Hd 3072
#define NE 4
#define Id 8192
#define BM 128
#define BK 64
#define RMAX 4608   // 36 tiles * 128; worst case 4096 + 4*127 padded

typedef __attribute__((ext_vector_type(8))) short short8;
typedef __attribute__((ext_vector_type(4))) float f32x4;

__device__ __forceinline__ unsigned short f2bf(float f) {
    unsigned u = __builtin_bit_cast(unsigned, f);
    u += 0x7FFFu + ((u >> 16) & 1u);   // RNE
    return (unsigned short)(u >> 16);
}

__device__ __forceinline__ void gload_lds16(const void* g, void* l) {
    __builtin_amdgcn_global_load_lds(
        (const __attribute__((address_space(1))) unsigned int*)g,
        (__attribute__((address_space(3))) unsigned int*)l,
        16, 0, 0);
}

// ---------------- gating: logits -> softmax -> top2 ----------------
__global__ void gate_topk_kernel(const float* __restrict__ x,
                                 const float* __restrict__ gw,
                                 int* __restrict__ tok_e,
                                 float* __restrict__ tok_v) {
    const int t = blockIdx.x;
    const int lane = threadIdx.x & 63;
    const int wave = threadIdx.x >> 6;   // = expert, NE==4 waves
    __shared__ float logits[NE];
    const float* xp = x + (size_t)t * Hd;
    const float* wp = gw + (size_t)wave * Hd;
    float s = 0.f;
    for (int h = lane; h < Hd; h += 64) s += xp[h] * wp[h];
#pragma unroll
    for (int o = 32; o > 0; o >>= 1) s += __shfl_xor(s, o);
    if (lane == 0) logits[wave] = s;
    __syncthreads();
    if (threadIdx.x == 0) {
        float m = logits[0];
#pragma unroll
        for (int e = 1; e < NE; e++) m = fmaxf(m, logits[e]);
        float p[NE]; float sum = 0.f;
#pragma unroll
        for (int e = 0; e < NE; e++) { p[e] = expf(logits[e] - m); sum += p[e]; }
        float inv = 1.f / sum;
#pragma unroll
        for (int e = 0; e < NE; e++) p[e] *= inv;
        // top-2, lax.top_k tie rule: lower index wins
        int e0 = 0; float v0 = p[0];
#pragma unroll
        for (int e = 1; e < NE; e++) if (p[e] > v0) { e0 = e; v0 = p[e]; }
        int e1 = -1; float v1 = -1.f;
#pragma unroll
        for (int e = 0; e < NE; e++) if (e != e0 && p[e] > v1) { e1 = e; v1 = p[e]; }
        tok_e[t * 2] = e0; tok_e[t * 2 + 1] = e1;
        tok_v[t * 2] = v0; tok_v[t * 2 + 1] = v1;
    }
}

// ---------------- routing: build 128-padded per-expert row lists ----------------
__global__ void route_kernel(const int* __restrict__ tok_e, const float* __restrict__ tok_v,
                             int* __restrict__ row_token, float* __restrict__ row_gate,
                             int* __restrict__ offsets) {
    __shared__ int cnt[NE], cur[NE], offs[NE + 1];
    const int tid = threadIdx.x;
    if (tid < NE) { cnt[tid] = 0; cur[tid] = 0; }
    __syncthreads();
    for (int i = tid; i < S * 2; i += 256) atomicAdd(&cnt[tok_e[i]], 1);
    __syncthreads();
    if (tid == 0) {
        int o = 0;
        for (int e = 0; e < NE; e++) { offs[e] = o; o += (cnt[e] + BM - 1) / BM * BM; }
        offs[NE] = o;
        for (int e = 0; e <= NE; e++) offsets[e] = offs[e];
    }
    __syncthreads();
    for (int r = tid; r < RMAX; r += 256) { row_token[r] = 0; row_gate[r] = 0.f; }
    __syncthreads();
    for (int i = tid; i < S * 2; i += 256) {
        int e = tok_e[i];
        int pos = atomicAdd(&cur[e], 1);
        int r = offs[e] + pos;
        row_token[r] = i >> 1;
        row_gate[r] = tok_v[i];
    }
}

// ---------------- x f32 -> bf16 ----------------
__global__ void cvt_x_kernel(const float* __restrict__ x, unsigned short* __restrict__ xb) {
    size_t i = ((size_t)blockIdx.x * blockDim.x + threadIdx.x) * 8;
    f32x4 a = *(const f32x4*)(x + i);
    f32x4 b = *(const f32x4*)(x + i + 4);
    union { unsigned short u[8]; short8 v; } o;
#pragma unroll
    for (int j = 0; j < 4; j++) { o.u[j] = f2bf(a[j]); o.u[4 + j] = f2bf(b[j]); }
    *(short8*)(xb + i) = o.v;
}

// ---------------- GEMM1: hidden = swiglu(x_rows . WguT) ----------------
// grid: (RMAX/BM, Id/128); block 256 (4 waves 2x2); each block: 128 rows x (128 gate + 128 up cols)
__global__ __launch_bounds__(256, 2)
void gemm1_kernel(const unsigned short* __restrict__ xb,
                  const float* __restrict__ wgu,
                  const int* __restrict__ row_token,
                  const int* __restrict__ offsets,
                  unsigned short* __restrict__ hidden) {
    __shared__ unsigned short As[BM][BK];
    __shared__ unsigned short Bg[BM][BK];
    __shared__ unsigned short Bu[BM][BK];

    const int rt = blockIdx.x, ct = blockIdx.y;
    const int rbase = rt * BM;
    const int off4 = offsets[4];
    if (rbase >= off4) return;
    int e = 3;
    if (rbase < offsets[1]) e = 0;
    else if (rbase < offsets[2]) e = 1;
    else if (rbase < offsets[3]) e = 2;

    const int tid = threadIdx.x;
    const int lane = tid & 63;
    const int wave = tid >> 6;
    const int wm = wave >> 1, wn = wave & 1;

    // A staging sources (global_load_lds, source pre-swizzled: slot ^= row&7)
    const unsigned short* asrc[4];
#pragma unroll
    for (int i2 = 0; i2 < 4; i2++) {
        int sgi = i2 * 4 + wave;                 // segment 0..15, wave-uniform
        int row = sgi * 8 + (lane >> 3);
        int g = (lane & 7) ^ (row & 7);
        int tok = row_token[rbase + row];
        asrc[i2] = xb + (size_t)tok * Hd + g * 8;
    }
    // B staging sources (reg-staged f32 -> bf16)
    const int col = tid >> 1;
    const int half = tid & 1;
    const size_t grow = (size_t)e * (2 * Id) + (size_t)ct * 128 + col;
    const float* bsrc_g = wgu + grow * Hd + half * 32;
    const float* bsrc_u = wgu + (grow + (size_t)Id) * Hd + half * 32;
    const int csw = col & 7;

    f32x4 accg[4][4], accu[4][4];
#pragma unroll
    for (int m = 0; m < 4; m++)
#pragma unroll
        for (int n = 0; n < 4; n++) { accg[m][n] = (f32x4)0.f; accu[m][n] = (f32x4)0.f; }

    for (int k0 = 0; k0 < Hd; k0 += BK) {
        __syncthreads();
        // A: 16KB via 16 wave-issues of 1KB
#pragma unroll
        for (int i2 = 0; i2 < 4; i2++) {
            int sgi = i2 * 4 + wave;
            gload_lds16(asrc[i2] + k0, &As[sgi * 8][0]);
        }
        // B: two 128x64 f32 panels -> bf16, swizzled ds_write_b128
        {
            const float* pg = bsrc_g + k0;
            const float* pu = bsrc_u + k0;
            f32x4 vg[8], vu[8];
#pragma unroll
            for (int j = 0; j < 8; j++) vg[j] = *(const f32x4*)(pg + j * 4);
#pragma unroll
            for (int j = 0; j < 8; j++) vu[j] = *(const f32x4*)(pu + j * 4);
#pragma unroll
            for (int j = 0; j < 4; j++) {
                union { unsigned short u[8]; short8 v8; } wg_, wu_;
#pragma unroll
                for (int q = 0; q < 4; q++) {
                    wg_.u[q] = f2bf(vg[2 * j][q]); wg_.u[4 + q] = f2bf(vg[2 * j + 1][q]);
                    wu_.u[q] = f2bf(vu[2 * j][q]); wu_.u[4 + q] = f2bf(vu[2 * j + 1][q]);
                }
                int gs = (half * 4 + j) ^ csw;
                *(short8*)&Bg[col][gs * 8] = wg_.v8;
                *(short8*)&Bu[col][gs * 8] = wu_.v8;
            }
        }
        __syncthreads();
#pragma unroll
        for (int kk = 0; kk < 2; kk++) {
            short8 af[4], bgf[4], buf_[4];
#pragma unroll
            for (int m = 0; m < 4; m++) {
                int r = wm * 64 + m * 16 + (lane & 15);
                int slot = (kk * 4 + (lane >> 4)) ^ (r & 7);
                af[m] = *(const short8*)&As[r][slot * 8];
            }
#pragma unroll
            for (int n = 0; n < 4; n++) {
                int c = wn * 64 + n * 16 + (lane & 15);
                int slot = (kk * 4 + (lane >> 4)) ^ (c & 7);
                bgf[n] = *(const short8*)&Bg[c][slot * 8];
                buf_[n] = *(const short8*)&Bu[c][slot * 8];
            }
#pragma unroll
            for (int m = 0; m < 4; m++)
#pragma unroll
                for (int n = 0; n < 4; n++) {
                    accg[m][n] = __builtin_amdgcn_mfma_f32_16x16x32_bf16(af[m], bgf[n], accg[m][n], 0, 0, 0);
                    accu[m][n] = __builtin_amdgcn_mfma_f32_16x16x32_bf16(af[m], buf_[n], accu[m][n], 0, 0, 0);
                }
        }
    }
    // epilogue: hidden = up * silu(gate), bf16
#pragma unroll
    for (int m = 0; m < 4; m++) {
#pragma unroll
        for (int n = 0; n < 4; n++) {
            int c = ct * 128 + wn * 64 + n * 16 + (lane & 15);
#pragma unroll
            for (int q = 0; q < 4; q++) {
                int r = rbase + wm * 64 + m * 16 + (lane >> 4) * 4 + q;
                float g = accg[m][n][q], u = accu[m][n][q];
                float hval = u * g / (1.f + expf(-g));
                hidden[(size_t)r * Id + c] = f2bf(hval);
            }
        }
    }
}

// ---------------- GEMM2: out[token] += gate * (hidden_rows . WdT) ----------------
// grid: (RMAX/BM, Hd/128); block 256 (4 waves 2x2)
__global__ __launch_bounds__(256, 2)
void gemm2_kernel(const unsigned short* __restrict__ hidden,
                  const float* __restrict__ wd,
                  const int* __restrict__ row_token,
                  const float* __restrict__ row_gate,
                  const int* __restrict__ offsets,
                  float* __restrict__ out) {
    __shared__ unsigned short As[BM][BK];
    __shared__ unsigned short Bs[BM][BK];

    const int rt = blockIdx.x, ct = blockIdx.y;
    const int rbase = rt * BM;
    const int off4 = offsets[4];
    if (rbase >= off4) return;
    int e = 3;
    if (rbase < offsets[1]) e = 0;
    else if (rbase < offsets[2]) e = 1;
    else if (rbase < offsets[3]) e = 2;

    const int tid = threadIdx.x;
    const int lane = tid & 63;
    const int wave = tid >> 6;
    const int wm = wave >> 1, wn = wave & 1;

    const unsigned short* asrc[4];
#pragma unroll
    for (int i2 = 0; i2 < 4; i2++) {
        int sgi = i2 * 4 + wave;
        int row = sgi * 8 + (lane >> 3);
        int g = (lane & 7) ^ (row & 7);
        asrc[i2] = hidden + (size_t)(rbase + row) * Id + g * 8;
    }
    const int col = tid >> 1;
    const int half = tid & 1;
    const float* bsrc = wd + ((size_t)e * Hd + (size_t)ct * 128 + col) * Id + half * 32;
    const int csw = col & 7;

    f32x4 acc[4][4];
#pragma unroll
    for (int m = 0; m < 4; m++)
#pragma unroll
        for (int n = 0; n < 4; n++) acc[m][n] = (f32x4)0.f;

    for (int k0 = 0; k0 < Id; k0 += BK) {
        __syncthreads();
#pragma unroll
        for (int i2 = 0; i2 < 4; i2++) {
            int sgi = i2 * 4 + wave;
            gload_lds16(asrc[i2] + k0, &As[sgi * 8][0]);
        }
        {
            const float* pb = bsrc + k0;
            f32x4 vb[8];
#pragma unroll
            for (int j = 0; j < 8; j++) vb[j] = *(const f32x4*)(pb + j * 4);
#pragma unroll
            for (int j = 0; j < 4; j++) {
                union { unsigned short u[8]; short8 v8; } wb_;
#pragma unroll
                for (int q = 0; q < 4; q++) {
                    wb_.u[q] = f2bf(vb[2 * j][q]); wb_.u[4 + q] = f2bf(vb[2 * j + 1][q]);
                }
                int gs = (half * 4 + j) ^ csw;
                *(short8*)&Bs[col][gs * 8] = wb_.v8;
            }
        }
        __syncthreads();
#pragma unroll
        for (int kk = 0; kk < 2; kk++) {
            short8 af[4], bf[4];
#pragma unroll
            for (int m = 0; m < 4; m++) {
                int r = wm * 64 + m * 16 + (lane & 15);
                int slot = (kk * 4 + (lane >> 4)) ^ (r & 7);
                af[m] = *(const short8*)&As[r][slot * 8];
            }
#pragma unroll
            for (int n = 0; n < 4; n++) {
                int c = wn * 64 + n * 16 + (lane & 15);
                int slot = (kk * 4 + (lane >> 4)) ^ (c & 7);
                bf[n] = *(const short8*)&Bs[c][slot * 8];
            }
#pragma unroll
            for (int m = 0; m < 4; m++)
#pragma unroll
                for (int n = 0; n < 4; n++)
                    acc[m][n] = __builtin_amdgcn_mfma_f32_16x16x32_bf16(af[m], bf[n], acc[m][n], 0, 0, 0);
        }
    }
#pragma unroll
    for (int m = 0; m < 4; m++) {
#pragma unroll
        for (int n = 0; n < 4; n++) {
            int c = ct * 128 + wn * 64 + n * 16 + (lane & 15);
#pragma unroll
            for (int q = 0; q < 4; q++) {
                int r = rbase + wm * 64 + m * 16 + (lane >> 4) * 4 + q;
                int tok = row_token[r];
                float gv = row_gate[r];
                if (gv != 0.f)
                    atomicAdd(&out[(size_t)tok * Hd + c], gv * acc[m][n][q]);
            }
        }
    }
}

extern "C" void kernel_launch(void* const* d_in, const int* in_sizes, int n_in,
                              void* d_out, int out_size, void* d_ws, size_t ws_size,
                              hipStream_t stream) {
    const float* x   = (const float*)d_in[0];
    const float* gw  = (const float*)d_in[1];
    const float* wgu = (const float*)d_in[2];
    const float* wd  = (const float*)d_in[3];
    float* out = (float*)d_out;

    char* ws = (char*)d_ws;
    size_t o = 0;
    auto alloc = [&](size_t bytes) { void* p = ws + o; o = (o + bytes + 255) & ~(size_t)255; return p; };
    unsigned short* xb      = (unsigned short*)alloc((size_t)S * Hd * 2);
    unsigned short* hidden  = (unsigned short*)alloc((size_t)RMAX * Id * 2);
    int*   row_token = (int*)alloc(RMAX * 4);
    float* row_gate  = (float*)alloc(RMAX * 4);
    int*   offsets   = (int*)alloc(8 * 4);
    int*   tok_e     = (int*)alloc(S * 2 * 4);
    float* tok_v     = (float*)alloc(S * 2 * 4);

    hipMemsetAsync(d_out, 0, (size_t)S * Hd * 4, stream);
    gate_topk_kernel<<<S, 256, 0, stream>>>(x, gw, tok_e, tok_v);
    route_kernel<<<1, 256, 0, stream>>>(tok_e, tok_v, row_token, row_gate, offsets);
    cvt_x_kernel<<<(S * Hd / 8) / 256, 256, 0, stream>>>(x, xb);
    gemm1_kernel<<<dim3(RMAX / BM, Id / 128), 256, 0, stream>>>(xb, wgu, row_token, offsets, hidden);
    gemm2_kernel<<<dim3(RMAX / BM, Hd / 128), 256, 0, stream>>>(hidden, wd, row_token, row_gate, offsets, out);
}

// Round 2
// 1380.762 us; speedup vs baseline: 1.7414x; 1.7414x over previous
//
#include <hip/hip_runtime.h>

#define S 2048
#define Hd 3072
#define NE 4
#define Id 8192
#define BM 128
#define BK 64
#define RMAX 4608   // 36 tiles * 128; worst case 4096 + 4*127 padded

typedef __attribute__((ext_vector_type(8))) short short8;
typedef __attribute__((ext_vector_type(4))) float f32x4;

__device__ __forceinline__ unsigned short f2bf(float f) {
    unsigned u = __builtin_bit_cast(unsigned, f);
    u += 0x7FFFu + ((u >> 16) & 1u);   // RNE
    return (unsigned short)(u >> 16);
}

__device__ __forceinline__ void gload_lds16(const void* g, void* l) {
    __builtin_amdgcn_global_load_lds(
        (const __attribute__((address_space(1))) unsigned int*)g,
        (__attribute__((address_space(3))) unsigned int*)l,
        16, 0, 0);
}

// ---------------- gating: logits -> softmax -> top2 ----------------
__global__ void gate_topk_kernel(const float* __restrict__ x,
                                 const float* __restrict__ gw,
                                 int* __restrict__ tok_e,
                                 float* __restrict__ tok_v) {
    const int t = blockIdx.x;
    const int lane = threadIdx.x & 63;
    const int wave = threadIdx.x >> 6;   // = expert, NE==4 waves
    __shared__ float logits[NE];
    const float* xp = x + (size_t)t * Hd;
    const float* wp = gw + (size_t)wave * Hd;
    float s = 0.f;
    for (int h = lane; h < Hd; h += 64) s += xp[h] * wp[h];
#pragma unroll
    for (int o = 32; o > 0; o >>= 1) s += __shfl_xor(s, o);
    if (lane == 0) logits[wave] = s;
    __syncthreads();
    if (threadIdx.x == 0) {
        float m = logits[0];
#pragma unroll
        for (int e = 1; e < NE; e++) m = fmaxf(m, logits[e]);
        float p[NE]; float sum = 0.f;
#pragma unroll
        for (int e = 0; e < NE; e++) { p[e] = expf(logits[e] - m); sum += p[e]; }
        float inv = 1.f / sum;
#pragma unroll
        for (int e = 0; e < NE; e++) p[e] *= inv;
        int e0 = 0; float v0 = p[0];
#pragma unroll
        for (int e = 1; e < NE; e++) if (p[e] > v0) { e0 = e; v0 = p[e]; }
        int e1 = -1; float v1 = -1.f;
#pragma unroll
        for (int e = 0; e < NE; e++) if (e != e0 && p[e] > v1) { e1 = e; v1 = p[e]; }
        tok_e[t * 2] = e0; tok_e[t * 2 + 1] = e1;
        tok_v[t * 2] = v0; tok_v[t * 2 + 1] = v1;
    }
}

// ---------------- routing: build 128-padded per-expert row lists ----------------
__global__ void route_kernel(const int* __restrict__ tok_e, const float* __restrict__ tok_v,
                             int* __restrict__ row_token, float* __restrict__ row_gate,
                             int* __restrict__ offsets) {
    __shared__ int cnt[NE], cur[NE], offs[NE + 1];
    const int tid = threadIdx.x;
    if (tid < NE) { cnt[tid] = 0; cur[tid] = 0; }
    __syncthreads();
    for (int i = tid; i < S * 2; i += 256) atomicAdd(&cnt[tok_e[i]], 1);
    __syncthreads();
    if (tid == 0) {
        int o = 0;
        for (int e = 0; e < NE; e++) { offs[e] = o; o += (cnt[e] + BM - 1) / BM * BM; }
        offs[NE] = o;
        for (int e = 0; e <= NE; e++) offsets[e] = offs[e];
    }
    __syncthreads();
    for (int r = tid; r < RMAX; r += 256) { row_token[r] = 0; row_gate[r] = 0.f; }
    __syncthreads();
    for (int i = tid; i < S * 2; i += 256) {
        int e = tok_e[i];
        int pos = atomicAdd(&cur[e], 1);
        int r = offs[e] + pos;
        row_token[r] = i >> 1;
        row_gate[r] = tok_v[i];
    }
}

// ---------------- generic f32 -> bf16 (grid-stride, 8 elems/thread) ----------------
__global__ void cvt_bf16_kernel(const float* __restrict__ src,
                                unsigned short* __restrict__ dst, size_t n8) {
    size_t stride = (size_t)gridDim.x * blockDim.x;
    for (size_t i = (size_t)blockIdx.x * blockDim.x + threadIdx.x; i < n8; i += stride) {
        size_t b = i * 8;
        f32x4 a = *(const f32x4*)(src + b);
        f32x4 c = *(const f32x4*)(src + b + 4);
        union { unsigned short u[8]; short8 v; } o;
#pragma unroll
        for (int j = 0; j < 4; j++) { o.u[j] = f2bf(a[j]); o.u[4 + j] = f2bf(c[j]); }
        *(short8*)(dst + b) = o.v;
    }
}

// ================= bf16-weight GEMMs (pre-converted path) =================

// GEMM1: hidden = swiglu(x_rows . WguT); grid (RMAX/BM, Id/128), 4 waves 2x2
__global__ __launch_bounds__(256, 2)
void gemm1_bf16_kernel(const unsigned short* __restrict__ xb,
                       const unsigned short* __restrict__ wgu_b,
                       const int* __restrict__ row_token,
                       const int* __restrict__ offsets,
                       unsigned short* __restrict__ hidden) {
    __shared__ unsigned short As[BM][BK];
    __shared__ unsigned short Bg[BM][BK];
    __shared__ unsigned short Bu[BM][BK];

    const int rt = blockIdx.x, ct = blockIdx.y;
    const int rbase = rt * BM;
    const int off4 = offsets[4];
    if (rbase >= off4) return;
    int e = 3;
    if (rbase < offsets[1]) e = 0;
    else if (rbase < offsets[2]) e = 1;
    else if (rbase < offsets[3]) e = 2;

    const int tid = threadIdx.x;
    const int lane = tid & 63;
    const int wave = tid >> 6;
    const int wm = wave >> 1, wn = wave & 1;

    // pre-swizzled global sources: lane l covers row sgi*8+(l>>3), slot (l&7)^(row&7)
    const unsigned short* asrc[4];
    const unsigned short* gsrc[4];
    const unsigned short* usrc[4];
#pragma unroll
    for (int i2 = 0; i2 < 4; i2++) {
        int sgi = i2 * 4 + wave;
        int row = sgi * 8 + (lane >> 3);
        int g = (lane & 7) ^ (row & 7);
        int tok = row_token[rbase + row];
        asrc[i2] = xb + (size_t)tok * Hd + g * 8;
        size_t growg = (size_t)e * (2 * Id) + (size_t)ct * 128 + row;
        gsrc[i2] = wgu_b + growg * Hd + g * 8;
        usrc[i2] = wgu_b + (growg + (size_t)Id) * Hd + g * 8;
    }

    f32x4 accg[4][4], accu[4][4];
#pragma unroll
    for (int m = 0; m < 4; m++)
#pragma unroll
        for (int n = 0; n < 4; n++) { accg[m][n] = (f32x4)0.f; accu[m][n] = (f32x4)0.f; }

    for (int k0 = 0; k0 < Hd; k0 += BK) {
        __syncthreads();
#pragma unroll
        for (int i2 = 0; i2 < 4; i2++) {
            int sgi = i2 * 4 + wave;
            gload_lds16(asrc[i2] + k0, &As[sgi * 8][0]);
            gload_lds16(gsrc[i2] + k0, &Bg[sgi * 8][0]);
            gload_lds16(usrc[i2] + k0, &Bu[sgi * 8][0]);
        }
        __syncthreads();
#pragma unroll
        for (int kk = 0; kk < 2; kk++) {
            short8 af[4], bgf[4], buf_[4];
#pragma unroll
            for (int m = 0; m < 4; m++) {
                int r = wm * 64 + m * 16 + (lane & 15);
                int slot = (kk * 4 + (lane >> 4)) ^ (r & 7);
                af[m] = *(const short8*)&As[r][slot * 8];
            }
#pragma unroll
            for (int n = 0; n < 4; n++) {
                int c = wn * 64 + n * 16 + (lane & 15);
                int slot = (kk * 4 + (lane >> 4)) ^ (c & 7);
                bgf[n] = *(const short8*)&Bg[c][slot * 8];
                buf_[n] = *(const short8*)&Bu[c][slot * 8];
            }
#pragma unroll
            for (int m = 0; m < 4; m++)
#pragma unroll
                for (int n = 0; n < 4; n++) {
                    accg[m][n] = __builtin_amdgcn_mfma_f32_16x16x32_bf16(af[m], bgf[n], accg[m][n], 0, 0, 0);
                    accu[m][n] = __builtin_amdgcn_mfma_f32_16x16x32_bf16(af[m], buf_[n], accu[m][n], 0, 0, 0);
                }
        }
    }
#pragma unroll
    for (int m = 0; m < 4; m++) {
#pragma unroll
        for (int n = 0; n < 4; n++) {
            int c = ct * 128 + wn * 64 + n * 16 + (lane & 15);
#pragma unroll
            for (int q = 0; q < 4; q++) {
                int r = rbase + wm * 64 + m * 16 + (lane >> 4) * 4 + q;
                float g = accg[m][n][q], u = accu[m][n][q];
                float hval = u * g / (1.f + expf(-g));
                hidden[(size_t)r * Id + c] = f2bf(hval);
            }
        }
    }
}

// GEMM2: out[token] += gate * (hidden_rows . WdT); grid (RMAX/BM, Hd/128)
__global__ __launch_bounds__(256, 3)
void gemm2_bf16_kernel(const unsigned short* __restrict__ hidden,
                       const unsigned short* __restrict__ wd_b,
                       const int* __restrict__ row_token,
                       const float* __restrict__ row_gate,
                       const int* __restrict__ offsets,
                       float* __restrict__ out) {
    __shared__ unsigned short As[BM][BK];
    __shared__ unsigned short Bs[BM][BK];

    const int rt = blockIdx.x, ct = blockIdx.y;
    const int rbase = rt * BM;
    const int off4 = offsets[4];
    if (rbase >= off4) return;
    int e = 3;
    if (rbase < offsets[1]) e = 0;
    else if (rbase < offsets[2]) e = 1;
    else if (rbase < offsets[3]) e = 2;

    const int tid = threadIdx.x;
    const int lane = tid & 63;
    const int wave = tid >> 6;
    const int wm = wave >> 1, wn = wave & 1;

    const unsigned short* asrc[4];
    const unsigned short* bsrc[4];
#pragma unroll
    for (int i2 = 0; i2 < 4; i2++) {
        int sgi = i2 * 4 + wave;
        int row = sgi * 8 + (lane >> 3);
        int g = (lane & 7) ^ (row & 7);
        asrc[i2] = hidden + (size_t)(rbase + row) * Id + g * 8;
        bsrc[i2] = wd_b + ((size_t)e * Hd + (size_t)ct * 128 + row) * Id + g * 8;
    }

    f32x4 acc[4][4];
#pragma unroll
    for (int m = 0; m < 4; m++)
#pragma unroll
        for (int n = 0; n < 4; n++) acc[m][n] = (f32x4)0.f;

    for (int k0 = 0; k0 < Id; k0 += BK) {
        __syncthreads();
#pragma unroll
        for (int i2 = 0; i2 < 4; i2++) {
            int sgi = i2 * 4 + wave;
            gload_lds16(asrc[i2] + k0, &As[sgi * 8][0]);
            gload_lds16(bsrc[i2] + k0, &Bs[sgi * 8][0]);
        }
        __syncthreads();
#pragma unroll
        for (int kk = 0; kk < 2; kk++) {
            short8 af[4], bf[4];
#pragma unroll
            for (int m = 0; m < 4; m++) {
                int r = wm * 64 + m * 16 + (lane & 15);
                int slot = (kk * 4 + (lane >> 4)) ^ (r & 7);
                af[m] = *(const short8*)&As[r][slot * 8];
            }
#pragma unroll
            for (int n = 0; n < 4; n++) {
                int c = wn * 64 + n * 16 + (lane & 15);
                int slot = (kk * 4 + (lane >> 4)) ^ (c & 7);
                bf[n] = *(const short8*)&Bs[c][slot * 8];
            }
#pragma unroll
            for (int m = 0; m < 4; m++)
#pragma unroll
                for (int n = 0; n < 4; n++)
                    acc[m][n] = __builtin_amdgcn_mfma_f32_16x16x32_bf16(af[m], bf[n], acc[m][n], 0, 0, 0);
        }
    }
#pragma unroll
    for (int m = 0; m < 4; m++) {
#pragma unroll
        for (int n = 0; n < 4; n++) {
            int c = ct * 128 + wn * 64 + n * 16 + (lane & 15);
#pragma unroll
            for (int q = 0; q < 4; q++) {
                int r = rbase + wm * 64 + m * 16 + (lane >> 4) * 4 + q;
                int tok = row_token[r];
                float gv = row_gate[r];
                if (gv != 0.f)
                    atomicAdd(&out[(size_t)tok * Hd + c], gv * acc[m][n][q]);
            }
        }
    }
}

// ================= f32-weight fused GEMMs (fallback if ws too small) =================

__global__ __launch_bounds__(256, 2)
void gemm1_f32_kernel(const unsigned short* __restrict__ xb,
                      const float* __restrict__ wgu,
                      const int* __restrict__ row_token,
                      const int* __restrict__ offsets,
                      unsigned short* __restrict__ hidden) {
    __shared__ unsigned short As[BM][BK];
    __shared__ unsigned short Bg[BM][BK];
    __shared__ unsigned short Bu[BM][BK];

    const int rt = blockIdx.x, ct = blockIdx.y;
    const int rbase = rt * BM;
    const int off4 = offsets[4];
    if (rbase >= off4) return;
    int e = 3;
    if (rbase < offsets[1]) e = 0;
    else if (rbase < offsets[2]) e = 1;
    else if (rbase < offsets[3]) e = 2;

    const int tid = threadIdx.x;
    const int lane = tid & 63;
    const int wave = tid >> 6;
    const int wm = wave >> 1, wn = wave & 1;

    const unsigned short* asrc[4];
#pragma unroll
    for (int i2 = 0; i2 < 4; i2++) {
        int sgi = i2 * 4 + wave;
        int row = sgi * 8 + (lane >> 3);
        int g = (lane & 7) ^ (row & 7);
        int tok = row_token[rbase + row];
        asrc[i2] = xb + (size_t)tok * Hd + g * 8;
    }
    const int col = tid >> 1;
    const int half = tid & 1;
    const size_t grow = (size_t)e * (2 * Id) + (size_t)ct * 128 + col;
    const float* bsrc_g = wgu + grow * Hd + half * 32;
    const float* bsrc_u = wgu + (grow + (size_t)Id) * Hd + half * 32;
    const int csw = col & 7;

    f32x4 accg[4][4], accu[4][4];
#pragma unroll
    for (int m = 0; m < 4; m++)
#pragma unroll
        for (int n = 0; n < 4; n++) { accg[m][n] = (f32x4)0.f; accu[m][n] = (f32x4)0.f; }

    for (int k0 = 0; k0 < Hd; k0 += BK) {
        __syncthreads();
#pragma unroll
        for (int i2 = 0; i2 < 4; i2++) {
            int sgi = i2 * 4 + wave;
            gload_lds16(asrc[i2] + k0, &As[sgi * 8][0]);
        }
        {
            const float* pg = bsrc_g + k0;
            const float* pu = bsrc_u + k0;
            f32x4 vg[8], vu[8];
#pragma unroll
            for (int j = 0; j < 8; j++) vg[j] = *(const f32x4*)(pg + j * 4);
#pragma unroll
            for (int j = 0; j < 8; j++) vu[j] = *(const f32x4*)(pu + j * 4);
#pragma unroll
            for (int j = 0; j < 4; j++) {
                union { unsigned short u[8]; short8 v8; } wg_, wu_;
#pragma unroll
                for (int q = 0; q < 4; q++) {
                    wg_.u[q] = f2bf(vg[2 * j][q]); wg_.u[4 + q] = f2bf(vg[2 * j + 1][q]);
                    wu_.u[q] = f2bf(vu[2 * j][q]); wu_.u[4 + q] = f2bf(vu[2 * j + 1][q]);
                }
                int gs = (half * 4 + j) ^ csw;
                *(short8*)&Bg[col][gs * 8] = wg_.v8;
                *(short8*)&Bu[col][gs * 8] = wu_.v8;
            }
        }
        __syncthreads();
#pragma unroll
        for (int kk = 0; kk < 2; kk++) {
            short8 af[4], bgf[4], buf_[4];
#pragma unroll
            for (int m = 0; m < 4; m++) {
                int r = wm * 64 + m * 16 + (lane & 15);
                int slot = (kk * 4 + (lane >> 4)) ^ (r & 7);
                af[m] = *(const short8*)&As[r][slot * 8];
            }
#pragma unroll
            for (int n = 0; n < 4; n++) {
                int c = wn * 64 + n * 16 + (lane & 15);
                int slot = (kk * 4 + (lane >> 4)) ^ (c & 7);
                bgf[n] = *(const short8*)&Bg[c][slot * 8];
                buf_[n] = *(const short8*)&Bu[c][slot * 8];
            }
#pragma unroll
            for (int m = 0; m < 4; m++)
#pragma unroll
                for (int n = 0; n < 4; n++) {
                    accg[m][n] = __builtin_amdgcn_mfma_f32_16x16x32_bf16(af[m], bgf[n], accg[m][n], 0, 0, 0);
                    accu[m][n] = __builtin_amdgcn_mfma_f32_16x16x32_bf16(af[m], buf_[n], accu[m][n], 0, 0, 0);
                }
        }
    }
#pragma unroll
    for (int m = 0; m < 4; m++) {
#pragma unroll
        for (int n = 0; n < 4; n++) {
            int c = ct * 128 + wn * 64 + n * 16 + (lane & 15);
#pragma unroll
            for (int q = 0; q < 4; q++) {
                int r = rbase + wm * 64 + m * 16 + (lane >> 4) * 4 + q;
                float g = accg[m][n][q], u = accu[m][n][q];
                float hval = u * g / (1.f + expf(-g));
                hidden[(size_t)r * Id + c] = f2bf(hval);
            }
        }
    }
}

__global__ __launch_bounds__(256, 2)
void gemm2_f32_kernel(const unsigned short* __restrict__ hidden,
                      const float* __restrict__ wd,
                      const int* __restrict__ row_token,
                      const float* __restrict__ row_gate,
                      const int* __restrict__ offsets,
                      float* __restrict__ out) {
    __shared__ unsigned short As[BM][BK];
    __shared__ unsigned short Bs[BM][BK];

    const int rt = blockIdx.x, ct = blockIdx.y;
    const int rbase = rt * BM;
    const int off4 = offsets[4];
    if (rbase >= off4) return;
    int e = 3;
    if (rbase < offsets[1]) e = 0;
    else if (rbase < offsets[2]) e = 1;
    else if (rbase < offsets[3]) e = 2;

    const int tid = threadIdx.x;
    const int lane = tid & 63;
    const int wave = tid >> 6;
    const int wm = wave >> 1, wn = wave & 1;

    const unsigned short* asrc[4];
#pragma unroll
    for (int i2 = 0; i2 < 4; i2++) {
        int sgi = i2 * 4 + wave;
        int row = sgi * 8 + (lane >> 3);
        int g = (lane & 7) ^ (row & 7);
        asrc[i2] = hidden + (size_t)(rbase + row) * Id + g * 8;
    }
    const int col = tid >> 1;
    const int half = tid & 1;
    const float* bsrc = wd + ((size_t)e * Hd + (size_t)ct * 128 + col) * Id + half * 32;
    const int csw = col & 7;

    f32x4 acc[4][4];
#pragma unroll
    for (int m = 0; m < 4; m++)
#pragma unroll
        for (int n = 0; n < 4; n++) acc[m][n] = (f32x4)0.f;

    for (int k0 = 0; k0 < Id; k0 += BK) {
        __syncthreads();
#pragma unroll
        for (int i2 = 0; i2 < 4; i2++) {
            int sgi = i2 * 4 + wave;
            gload_lds16(asrc[i2] + k0, &As[sgi * 8][0]);
        }
        {
            const float* pb = bsrc + k0;
            f32x4 vb[8];
#pragma unroll
            for (int j = 0; j < 8; j++) vb[j] = *(const f32x4*)(pb + j * 4);
#pragma unroll
            for (int j = 0; j < 4; j++) {
                union { unsigned short u[8]; short8 v8; } wb_;
#pragma unroll
                for (int q = 0; q < 4; q++) {
                    wb_.u[q] = f2bf(vb[2 * j][q]); wb_.u[4 + q] = f2bf(vb[2 * j + 1][q]);
                }
                int gs = (half * 4 + j) ^ csw;
                *(short8*)&Bs[col][gs * 8] = wb_.v8;
            }
        }
        __syncthreads();
#pragma unroll
        for (int kk = 0; kk < 2; kk++) {
            short8 af[4], bf[4];
#pragma unroll
            for (int m = 0; m < 4; m++) {
                int r = wm * 64 + m * 16 + (lane & 15);
                int slot = (kk * 4 + (lane >> 4)) ^ (r & 7);
                af[m] = *(const short8*)&As[r][slot * 8];
            }
#pragma unroll
            for (int n = 0; n < 4; n++) {
                int c = wn * 64 + n * 16 + (lane & 15);
                int slot = (kk * 4 + (lane >> 4)) ^ (c & 7);
                bf[n] = *(const short8*)&Bs[c][slot * 8];
            }
#pragma unroll
            for (int m = 0; m < 4; m++)
#pragma unroll
                for (int n = 0; n < 4; n++)
                    acc[m][n] = __builtin_amdgcn_mfma_f32_16x16x32_bf16(af[m], bf[n], acc[m][n], 0, 0, 0);
        }
    }
#pragma unroll
    for (int m = 0; m < 4; m++) {
#pragma unroll
        for (int n = 0; n < 4; n++) {
            int c = ct * 128 + wn * 64 + n * 16 + (lane & 15);
#pragma unroll
            for (int q = 0; q < 4; q++) {
                int r = rbase + wm * 64 + m * 16 + (lane >> 4) * 4 + q;
                int tok = row_token[r];
                float gv = row_gate[r];
                if (gv != 0.f)
                    atomicAdd(&out[(size_t)tok * Hd + c], gv * acc[m][n][q]);
            }
        }
    }
}

extern "C" void kernel_launch(void* const* d_in, const int* in_sizes, int n_in,
                              void* d_out, int out_size, void* d_ws, size_t ws_size,
                              hipStream_t stream) {
    const float* x   = (const float*)d_in[0];
    const float* gw  = (const float*)d_in[1];
    const float* wgu = (const float*)d_in[2];
    const float* wd  = (const float*)d_in[3];
    float* out = (float*)d_out;

    const size_t n_wgu = (size_t)NE * 2 * Id * Hd;   // 201.3M elems
    const size_t n_wd  = (size_t)NE * Hd * Id;       // 100.7M elems

    char* ws = (char*)d_ws;
    size_t o = 0;
    auto alloc = [&](size_t bytes) { void* p = ws + o; o = (o + bytes + 255) & ~(size_t)255; return p; };
    unsigned short* xb      = (unsigned short*)alloc((size_t)S * Hd * 2);
    unsigned short* hidden  = (unsigned short*)alloc((size_t)RMAX * Id * 2);
    int*   row_token = (int*)alloc(RMAX * 4);
    float* row_gate  = (float*)alloc(RMAX * 4);
    int*   offsets   = (int*)alloc(8 * 4);
    int*   tok_e     = (int*)alloc(S * 2 * 4);
    float* tok_v     = (float*)alloc(S * 2 * 4);
    size_t base_need = o;
    unsigned short* wgu_b = (unsigned short*)alloc(n_wgu * 2);
    unsigned short* wd_b  = (unsigned short*)alloc(n_wd * 2);
    const bool big = (ws_size >= o);

    hipMemsetAsync(d_out, 0, (size_t)S * Hd * 4, stream);
    gate_topk_kernel<<<S, 256, 0, stream>>>(x, gw, tok_e, tok_v);
    route_kernel<<<1, 256, 0, stream>>>(tok_e, tok_v, row_token, row_gate, offsets);
    cvt_bf16_kernel<<<1024, 256, 0, stream>>>(x, xb, (size_t)S * Hd / 8);

    if (big) {
        cvt_bf16_kernel<<<2048, 256, 0, stream>>>(wgu, wgu_b, n_wgu / 8);
        cvt_bf16_kernel<<<2048, 256, 0, stream>>>(wd, wd_b, n_wd / 8);
        gemm1_bf16_kernel<<<dim3(RMAX / BM, Id / 128), 256, 0, stream>>>(
            xb, wgu_b, row_token, offsets, hidden);
        gemm2_bf16_kernel<<<dim3(RMAX / BM, Hd / 128), 256, 0, stream>>>(
            hidden, wd_b, row_token, row_gate, offsets, out);
    } else {
        (void)base_need;
        gemm1_f32_kernel<<<dim3(RMAX / BM, Id / 128), 256, 0, stream>>>(
            xb, wgu, row_token, offsets, hidden);
        gemm2_f32_kernel<<<dim3(RMAX / BM, Hd / 128), 256, 0, stream>>>(
            hidden, wd, row_token, row_gate, offsets, out);
    }
}